// Round 2
// baseline (17916.187 us; speedup 1.0000x reference)
//
#include <hip/hip_runtime.h>

#define HH 192
#define WW 384
#define CC 16
#define OH 184
#define OW 376
#define NGRP 2
#define NTAP 25
#define TPX 10          // pixel-threads per quad
#define PX 8            // consecutive ox pixels per thread
#define TILE_OX (TPX*PX) // 80 pixels per block

// Kernel A: S[b][y][x] = sum_c volume[b][y][x][c]
__global__ void sumc_kernel(const float* __restrict__ vol, float* __restrict__ S, int n) {
    int idx = blockIdx.x * blockDim.x + threadIdx.x;
    if (idx >= n) return;
    const float4* p = reinterpret_cast<const float4*>(vol + (size_t)idx * CC);
    float4 a = p[0], b = p[1], c = p[2], d = p[3];
    float s = ((a.x + a.y) + (a.z + a.w)) + ((b.x + b.y) + (b.z + b.w))
            + ((c.x + c.y) + (c.z + c.w)) + ((d.x + d.y) + (d.z + d.w));
    S[idx] = s;
}

// Fused dilated 5x5 offset conv + bilinear sampling.
// Block: 256 threads (250 active) = 25 n-quads x 10 px-threads; 80 ox pixels/block.
// Each thread: 8 consecutive pixels, one n-quad (tap tn): acc[j] = {dy_g0,dy_g1,dx_g0,dx_g1}.
// Register reuse: per (ky,cq) a 16-column slice of the volume row lives in regs and
// feeds all 5 kx taps -> 16 v-loads + 20 w-loads per 640 FMAs.
__global__ __launch_bounds__(256) void dconv_kernel(
    const float* __restrict__ vol, const float* __restrict__ w_off,
    const float* __restrict__ b_off, const float* __restrict__ S,
    float* __restrict__ out)
{
    const int tid = threadIdx.x;
    const int tn  = tid / TPX;   // n-quad / tap 0..24
    const int tpx = tid % TPX;
    if (tn >= NTAP) return;

    const int oy = blockIdx.y;
    const int b  = blockIdx.z;
    const int ox0 = blockIdx.x * TILE_OX + tpx * PX;

    // clamped column indices for the 16-wide register slice (cols ox0..ox0+15)
    int colc[PX + 8];
    #pragma unroll
    for (int jj = 0; jj < PX + 8; ++jj) {
        int c = ox0 + jj;
        colc[jj] = c < WW ? c : (WW - 1);
    }

    const float4 bo = *reinterpret_cast<const float4*>(b_off + 4 * tn);
    float4 acc[PX];
    #pragma unroll
    for (int j = 0; j < PX; ++j) acc[j] = bo;

    #pragma unroll
    for (int ky = 0; ky < 5; ++ky) {
        const float* __restrict__ vrow = vol + ((b * HH + oy + 2 * ky) * WW) * CC;
        #pragma unroll
        for (int cq = 0; cq < 4; ++cq) {
            // 16-column slice of this row's channel quad
            float4 v[PX + 8];
            #pragma unroll
            for (int jj = 0; jj < PX + 8; ++jj)
                v[jj] = *reinterpret_cast<const float4*>(vrow + colc[jj] * CC + 4 * cq);
            #pragma unroll
            for (int kx = 0; kx < 5; ++kx) {
                const float* __restrict__ wp =
                    w_off + 4 * tn + ((ky * 5 + kx) * CC + 4 * cq) * 100;
                const float4 w0 = *reinterpret_cast<const float4*>(wp + 0 * 100);
                const float4 w1 = *reinterpret_cast<const float4*>(wp + 1 * 100);
                const float4 w2 = *reinterpret_cast<const float4*>(wp + 2 * 100);
                const float4 w3 = *reinterpret_cast<const float4*>(wp + 3 * 100);
                #pragma unroll
                for (int j = 0; j < PX; ++j) {
                    const float4 vv = v[j + 2 * kx];
                    acc[j].x += vv.x * w0.x + vv.y * w1.x + vv.z * w2.x + vv.w * w3.x;
                    acc[j].y += vv.x * w0.y + vv.y * w1.y + vv.z * w2.y + vv.w * w3.y;
                    acc[j].z += vv.x * w0.z + vv.y * w1.z + vv.z * w2.z + vv.w * w3.z;
                    acc[j].w += vv.x * w0.w + vv.y * w1.w + vv.z * w2.w + vv.w * w3.w;
                }
            }
        }
    }

    // Sampling epilogue
    const int ky_t = tn / 5, kx_t = tn % 5;
    const float kv = (float)(2 * ky_t - 4);
    const float ku = (float)(2 * kx_t - 4);
    const float byv = (float)(4 + oy);
    const float* __restrict__ Sb = S + b * HH * WW;

    #pragma unroll
    for (int j = 0; j < PX; ++j) {
        const int ox = ox0 + j;
        if (ox >= OW) continue;
        #pragma unroll
        for (int g = 0; g < NGRP; ++g) {
            float dy = (g == 0) ? acc[j].x : acc[j].y;
            float dx = (g == 0) ? acc[j].z : acc[j].w;
            float rx = kv + dy;      // pairs with W axis (reference quirk)
            float ry = ku + dx;      // pairs with H axis
            int x0 = (int)rx;        // trunc-toward-zero == astype(int32)
            int x1 = x0 + 1;
            int y0 = (int)ry;
            int y1 = y0 + 1;
            int x0c = min(max(x0, 0), WW - 1);
            int x1c = min(max(x1, 0), WW - 1);
            int y0c = min(max(y0, 0), HH - 1);
            int y1c = min(max(y1, 0), HH - 1);
            float fx0 = (float)x0c, fx1 = (float)x1c;
            float fy0 = (float)y0c, fy1 = (float)y1c;
            float w0v = (fy1 - ry) * (fx1 - rx);
            float w1v = (fy1 - byv) * (rx - fx0);
            float w2v = (ry - fy0) * (fx1 - rx);
            float w3v = (ry - fy0) * (rx - fx0);
            float s00 = Sb[y0c * WW + x0c];
            float s01 = Sb[y0c * WW + x1c];
            float s10 = Sb[y1c * WW + x0c];
            float s11 = Sb[y1c * WW + x1c];
            float o = w0v * s00 + w1v * s01 + w2v * s10 + w3v * s11;
            out[(((b * NGRP + g) * OH + oy) * OW + ox) * NTAP + tn] = o;
        }
    }
}

extern "C" void kernel_launch(void* const* d_in, const int* in_sizes, int n_in,
                              void* d_out, int out_size, void* d_ws, size_t ws_size,
                              hipStream_t stream) {
    const float* vol   = (const float*)d_in[0];
    const float* w_off = (const float*)d_in[1];
    const float* b_off = (const float*)d_in[2];
    float* out = (float*)d_out;
    float* S   = (float*)d_ws;              // 2*192*384 floats = 576 KiB

    const int nS = 2 * HH * WW;
    sumc_kernel<<<(nS + 255) / 256, 256, 0, stream>>>(vol, S, nS);

    dim3 grid((OW + TILE_OX - 1) / TILE_OX, OH, 2);   // 5 x 184 x 2
    dconv_kernel<<<grid, 256, 0, stream>>>(vol, w_off, b_off, S, out);
}

// Round 3
// 390.470 us; speedup vs baseline: 45.8837x; 45.8837x over previous
//
#include <hip/hip_runtime.h>

#define HH 192
#define WW 384
#define CC 16
#define OH 184
#define OW 376
#define NTAP 25
#define TILE 64
#define PADC 73

// Kernel A: S[b][y][x] = sum_c volume[b][y][x][c]
__global__ void sumc_kernel(const float* __restrict__ vol, float* __restrict__ S, int n) {
    int idx = blockIdx.x * blockDim.x + threadIdx.x;
    if (idx >= n) return;
    const float4* p = reinterpret_cast<const float4*>(vol + (size_t)idx * CC);
    float4 a = p[0], b = p[1], c = p[2], d = p[3];
    S[idx] = ((a.x + a.y) + (a.z + a.w)) + ((b.x + b.y) + (b.z + b.w))
           + ((c.x + c.y) + (c.z + c.w)) + ((d.x + d.y) + (d.z + d.w));
}

// Kernel B: transpose weights so each tap's n-quad is contiguous:
// w_t[tn][kk][c][j] = w_off[kk][c][4*tn + j],  tn,kk in [0,25), c in [0,16)
__global__ void wtrans_kernel(const float* __restrict__ w_off, float4* __restrict__ w_t) {
    int i = blockIdx.x * 256 + threadIdx.x;     // i = ((tn*25+kk)*16+c)
    if (i >= NTAP * 25 * 16) return;
    int c  = i & 15;
    int kk = (i >> 4) % 25;
    int tn = i / (25 * 16);
    w_t[i] = *reinterpret_cast<const float4*>(w_off + (kk * 16 + c) * 100 + 4 * tn);
}

// Fused dilated 5x5 offset conv + bilinear sampling.
// Block: 320 threads = 5 waves; wave w owns output n-quad tn = kg*5 + w (wave-uniform
// -> weights via scalar loads). 64 pixels per block (lane = pixel). Volume tile
// (5 rows x 72 cols x 16ch, 23 KB) staged in LDS, shared by all 5 waves and all kx.
// Per (r,kx) step: 4 ds_read_b128 + 64 fp32 FMAs with SGPR weight operands.
__global__ __launch_bounds__(320) void dconv_kernel(
    const float* __restrict__ vol, const float* __restrict__ w_t,
    const float* __restrict__ b_off, const float* __restrict__ S,
    float* __restrict__ out)
{
    __shared__ float4 lds[4][5][PADC];   // [ch-quad][row][col], col stride 16B

    const int tid  = threadIdx.x;
    const int lane = tid & 63;
    const int wid  = tid >> 6;          // 0..4
    const int oy   = blockIdx.y;
    const int bz   = blockIdx.z;        // b*5 + kg
    const int b    = bz / 5;
    const int kg   = bz % 5;
    const int ox0  = blockIdx.x * TILE;
    const int tn   = __builtin_amdgcn_readfirstlane(kg * 5 + wid);  // tap 0..24, uniform

    // ---- stage volume tile: rows oy+2r (r=0..4), cols ox0..ox0+71 (clamped), 16 ch
    {
        const float* __restrict__ vb = vol + (size_t)(b * HH + oy) * WW * CC;
        for (int i = tid; i < 5 * 72 * 4; i += 320) {
            int q    = i & 3;
            int colr = (i >> 2) % 72;
            int r    = i / (72 * 4);
            int colg = ox0 + colr; if (colg > WW - 1) colg = WW - 1;
            lds[q][r][colr] = *reinterpret_cast<const float4*>(vb + (2 * r * WW + colg) * CC + 4 * q);
        }
    }
    __syncthreads();

    // ---- conv main loop
    const float* __restrict__ wt = w_t + tn * (25 * 16 * 4);   // uniform pointer
    const float4 bo = *reinterpret_cast<const float4*>(b_off + 4 * tn);
    float ax = bo.x, ay = bo.y, az = bo.z, aw = bo.w;

    for (int r = 0; r < 5; ++r) {
        #pragma unroll
        for (int kx = 0; kx < 5; ++kx) {
            const int cl = lane + 2 * kx;
            const float4 v0 = lds[0][r][cl];
            const float4 v1 = lds[1][r][cl];
            const float4 v2 = lds[2][r][cl];
            const float4 v3 = lds[3][r][cl];
            const float4* __restrict__ wq =
                reinterpret_cast<const float4*>(wt + (r * 5 + kx) * 64);
            #define QSTEP(vc, cb) { \
                const float4 w0 = wq[(cb)+0], w1 = wq[(cb)+1], w2 = wq[(cb)+2], w3 = wq[(cb)+3]; \
                ax += vc.x*w0.x + vc.y*w1.x + vc.z*w2.x + vc.w*w3.x; \
                ay += vc.x*w0.y + vc.y*w1.y + vc.z*w2.y + vc.w*w3.y; \
                az += vc.x*w0.z + vc.y*w1.z + vc.z*w2.z + vc.w*w3.z; \
                aw += vc.x*w0.w + vc.y*w1.w + vc.z*w2.w + vc.w*w3.w; }
            QSTEP(v0, 0) QSTEP(v1, 4) QSTEP(v2, 8) QSTEP(v3, 12)
            #undef QSTEP
        }
    }

    // ---- sampling epilogue: lane's pixel, tap tn, groups g=0,1
    const int ox = ox0 + lane;
    if (ox < OW) {
        const int kyt = tn / 5, kxt = tn % 5;
        const float kv  = (float)(2 * kyt - 4);
        const float ku  = (float)(2 * kxt - 4);
        const float byv = (float)(4 + oy);
        const float* __restrict__ Sb = S + b * HH * WW;
        const float dyv0 = ax, dyv1 = ay, dxv0 = az, dxv1 = aw;
        #pragma unroll
        for (int g = 0; g < 2; ++g) {
            const float dy = g == 0 ? dyv0 : dyv1;
            const float dx = g == 0 ? dxv0 : dxv1;
            const float rx = kv + dy;     // pairs with W axis (reference quirk)
            const float ry = ku + dx;     // pairs with H axis
            int x0 = (int)rx;             // trunc-toward-zero == astype(int32)
            int x1 = x0 + 1;
            int y0 = (int)ry;
            int y1 = y0 + 1;
            int x0c = min(max(x0, 0), WW - 1);
            int x1c = min(max(x1, 0), WW - 1);
            int y0c = min(max(y0, 0), HH - 1);
            int y1c = min(max(y1, 0), HH - 1);
            const float fx0 = (float)x0c, fx1 = (float)x1c;
            const float fy0 = (float)y0c, fy1 = (float)y1c;
            const float w0v = (fy1 - ry)  * (fx1 - rx);
            const float w1v = (fy1 - byv) * (rx - fx0);
            const float w2v = (ry - fy0)  * (fx1 - rx);
            const float w3v = (ry - fy0)  * (rx - fx0);
            const float s00 = Sb[y0c * WW + x0c];
            const float s01 = Sb[y0c * WW + x1c];
            const float s10 = Sb[y1c * WW + x0c];
            const float s11 = Sb[y1c * WW + x1c];
            out[(size_t)(((b * 2 + g) * OH + oy) * OW + ox) * NTAP + tn]
                = w0v * s00 + w1v * s01 + w2v * s10 + w3v * s11;
        }
    }
}

extern "C" void kernel_launch(void* const* d_in, const int* in_sizes, int n_in,
                              void* d_out, int out_size, void* d_ws, size_t ws_size,
                              hipStream_t stream) {
    const float* vol   = (const float*)d_in[0];
    const float* w_off = (const float*)d_in[1];
    const float* b_off = (const float*)d_in[2];
    float* out = (float*)d_out;

    float* S   = (float*)d_ws;                                   // 147456 floats = 576 KiB
    float* w_t = (float*)((char*)d_ws + 2 * HH * WW * 4);        // 10000 float4 = 160 KB

    const int nS = 2 * HH * WW;
    sumc_kernel<<<(nS + 255) / 256, 256, 0, stream>>>(vol, S, nS);

    const int nW = NTAP * 25 * 16;
    wtrans_kernel<<<(nW + 255) / 256, 256, 0, stream>>>(w_off, (float4*)w_t);

    dim3 grid((OW + TILE - 1) / TILE, OH, 2 * 5);   // 6 x 184 x 10
    dconv_kernel<<<grid, 320, 0, stream>>>(vol, w_t, b_off, S, out);
}

// Round 4
// 223.669 us; speedup vs baseline: 80.1013x; 1.7457x over previous
//
#include <hip/hip_runtime.h>

#define HH 192
#define WW 384
#define CC 16
#define OH 184
#define OW 376
#define NTAP 25
#define TILE 64
#define PADC 73

// Kernel A: S[b][y][x] = sum_c volume[b][y][x][c]
__global__ void sumc_kernel(const float* __restrict__ vol, float* __restrict__ S, int n) {
    int idx = blockIdx.x * blockDim.x + threadIdx.x;
    if (idx >= n) return;
    const float4* p = reinterpret_cast<const float4*>(vol + (size_t)idx * CC);
    float4 a = p[0], b = p[1], c = p[2], d = p[3];
    S[idx] = ((a.x + a.y) + (a.z + a.w)) + ((b.x + b.y) + (b.z + b.w))
           + ((c.x + c.y) + (c.z + c.w)) + ((d.x + d.y) + (d.z + d.w));
}

// Kernel B: transpose weights: w_t[tn][kk][c][j] = w_off[kk][c][4*tn+j]
__global__ void wtrans_kernel(const float* __restrict__ w_off, float4* __restrict__ w_t) {
    int i = blockIdx.x * 256 + threadIdx.x;     // i = ((tn*25+kk)*16+c)
    if (i >= NTAP * 25 * 16) return;
    int kk = (i >> 4) % 25;
    int tn = i / (25 * 16);
    w_t[i] = *reinterpret_cast<const float4*>(w_off + ((i & 15) + kk * 16) * 100 + 4 * tn);
}

// 64 pure-FMA dot: acc.{x,y,z,w} += sum over 16 channels (4 quads v0..v3) of v[c]*W[c].{x,y,z,w}
#define DOT16(acc, v0, v1, v2, v3, W) do {                                     \
    acc.x = fmaf(v0.x, W[0].x,  acc.x); acc.x = fmaf(v0.y, W[1].x,  acc.x);    \
    acc.x = fmaf(v0.z, W[2].x,  acc.x); acc.x = fmaf(v0.w, W[3].x,  acc.x);    \
    acc.x = fmaf(v1.x, W[4].x,  acc.x); acc.x = fmaf(v1.y, W[5].x,  acc.x);    \
    acc.x = fmaf(v1.z, W[6].x,  acc.x); acc.x = fmaf(v1.w, W[7].x,  acc.x);    \
    acc.x = fmaf(v2.x, W[8].x,  acc.x); acc.x = fmaf(v2.y, W[9].x,  acc.x);    \
    acc.x = fmaf(v2.z, W[10].x, acc.x); acc.x = fmaf(v2.w, W[11].x, acc.x);    \
    acc.x = fmaf(v3.x, W[12].x, acc.x); acc.x = fmaf(v3.y, W[13].x, acc.x);    \
    acc.x = fmaf(v3.z, W[14].x, acc.x); acc.x = fmaf(v3.w, W[15].x, acc.x);    \
    acc.y = fmaf(v0.x, W[0].y,  acc.y); acc.y = fmaf(v0.y, W[1].y,  acc.y);    \
    acc.y = fmaf(v0.z, W[2].y,  acc.y); acc.y = fmaf(v0.w, W[3].y,  acc.y);    \
    acc.y = fmaf(v1.x, W[4].y,  acc.y); acc.y = fmaf(v1.y, W[5].y,  acc.y);    \
    acc.y = fmaf(v1.z, W[6].y,  acc.y); acc.y = fmaf(v1.w, W[7].y,  acc.y);    \
    acc.y = fmaf(v2.x, W[8].y,  acc.y); acc.y = fmaf(v2.y, W[9].y,  acc.y);    \
    acc.y = fmaf(v2.z, W[10].y, acc.y); acc.y = fmaf(v2.w, W[11].y, acc.y);    \
    acc.y = fmaf(v3.x, W[12].y, acc.y); acc.y = fmaf(v3.y, W[13].y, acc.y);    \
    acc.y = fmaf(v3.z, W[14].y, acc.y); acc.y = fmaf(v3.w, W[15].y, acc.y);    \
    acc.z = fmaf(v0.x, W[0].z,  acc.z); acc.z = fmaf(v0.y, W[1].z,  acc.z);    \
    acc.z = fmaf(v0.z, W[2].z,  acc.z); acc.z = fmaf(v0.w, W[3].z,  acc.z);    \
    acc.z = fmaf(v1.x, W[4].z,  acc.z); acc.z = fmaf(v1.y, W[5].z,  acc.z);    \
    acc.z = fmaf(v1.z, W[6].z,  acc.z); acc.z = fmaf(v1.w, W[7].z,  acc.z);    \
    acc.z = fmaf(v2.x, W[8].z,  acc.z); acc.z = fmaf(v2.y, W[9].z,  acc.z);    \
    acc.z = fmaf(v2.z, W[10].z, acc.z); acc.z = fmaf(v2.w, W[11].z, acc.z);    \
    acc.z = fmaf(v3.x, W[12].z, acc.z); acc.z = fmaf(v3.y, W[13].z, acc.z);    \
    acc.z = fmaf(v3.z, W[14].z, acc.z); acc.z = fmaf(v3.w, W[15].z, acc.z);    \
    acc.w = fmaf(v0.x, W[0].w,  acc.w); acc.w = fmaf(v0.y, W[1].w,  acc.w);    \
    acc.w = fmaf(v0.z, W[2].w,  acc.w); acc.w = fmaf(v0.w, W[3].w,  acc.w);    \
    acc.w = fmaf(v1.x, W[4].w,  acc.w); acc.w = fmaf(v1.y, W[5].w,  acc.w);    \
    acc.w = fmaf(v1.z, W[6].w,  acc.w); acc.w = fmaf(v1.w, W[7].w,  acc.w);    \
    acc.w = fmaf(v2.x, W[8].w,  acc.w); acc.w = fmaf(v2.y, W[9].w,  acc.w);    \
    acc.w = fmaf(v2.z, W[10].w, acc.w); acc.w = fmaf(v2.w, W[11].w, acc.w);    \
    acc.w = fmaf(v3.x, W[12].w, acc.w); acc.w = fmaf(v3.y, W[13].w, acc.w);    \
    acc.w = fmaf(v3.z, W[14].w, acc.w); acc.w = fmaf(v3.w, W[15].w, acc.w);    \
} while (0)

// Fused dilated 5x5 offset conv + bilinear sampling, paired output rows.
// Block: 320 thr = 5 waves; wave = tap tn (uniform -> scalar weight loads).
// Computes oy0 = 4*by+p and oy1 = oy0+2, which share 4/5 dilated input rows:
// 6-row LDS tile; each weight s_load feeds 128 FMAs (two accumulator quads).
__global__ __launch_bounds__(320) void dconv_kernel(
    const float* __restrict__ vol, const float* __restrict__ w_t,
    const float* __restrict__ b_off, const float* __restrict__ S,
    float* __restrict__ out)
{
    __shared__ float4 lds[4][6][PADC];   // [ch-quad][row][col]

    const int tid  = threadIdx.x;
    const int lane = tid & 63;
    const int wid  = tid >> 6;          // 0..4
    const int z    = blockIdx.z;        // ((b*2+p)*5 + kg)
    const int kg   = z % 5;
    const int rem  = z / 5;
    const int p    = rem & 1;
    const int b    = rem >> 1;
    const int oy0  = 4 * blockIdx.y + p;
    const int oy1  = oy0 + 2;
    const int ox0  = blockIdx.x * TILE;
    const int tn   = __builtin_amdgcn_readfirstlane(kg * 5 + wid);

    // stage 6 rows (oy0+2r, r=0..5), cols ox0..ox0+71 (clamped), 16 ch
    {
        const float* __restrict__ vb = vol + (size_t)(b * HH + oy0) * WW * CC;
        for (int i = tid; i < 6 * 72 * 4; i += 320) {
            int q    = i & 3;
            int t    = i >> 2;
            int colr = t % 72;
            int r    = t / 72;
            int colg = ox0 + colr; if (colg > WW - 1) colg = WW - 1;
            lds[q][r][colr] = *reinterpret_cast<const float4*>(vb + (2 * r * WW + colg) * CC + 4 * q);
        }
    }
    __syncthreads();

    const float* __restrict__ wt = w_t + tn * (25 * 16 * 4);   // uniform
    const float4 bo = *reinterpret_cast<const float4*>(b_off + 4 * tn);
    float4 accA = bo, accB = bo;

    #pragma unroll 1
    for (int r = 0; r < 5; ++r) {
        #pragma unroll
        for (int kx = 0; kx < 5; ++kx) {
            const float4* __restrict__ W =
                reinterpret_cast<const float4*>(wt + (r * 5 + kx) * 64);
            const int cl = lane + 2 * kx;
            const float4 a0 = lds[0][r][cl], a1 = lds[1][r][cl];
            const float4 a2 = lds[2][r][cl], a3 = lds[3][r][cl];
            const float4 b0 = lds[0][r + 1][cl], b1 = lds[1][r + 1][cl];
            const float4 b2 = lds[2][r + 1][cl], b3 = lds[3][r + 1][cl];
            DOT16(accA, a0, a1, a2, a3, W);
            DOT16(accB, b0, b1, b2, b3, W);
        }
    }

    // sampling epilogue: lane's pixel, tap tn, 2 rows x 2 groups
    const int ox = ox0 + lane;
    if (ox < OW) {
        const int kyt = tn / 5, kxt = tn % 5;
        const float kv = (float)(2 * kyt - 4);
        const float ku = (float)(2 * kxt - 4);
        const float* __restrict__ Sb = S + b * HH * WW;
        #pragma unroll
        for (int rr = 0; rr < 2; ++rr) {
            const int oy = rr == 0 ? oy0 : oy1;
            const float4 acc = rr == 0 ? accA : accB;
            const float byv = (float)(4 + oy);
            #pragma unroll
            for (int g = 0; g < 2; ++g) {
                const float dy = g == 0 ? acc.x : acc.y;
                const float dx = g == 0 ? acc.z : acc.w;
                const float rx = kv + dy;     // pairs with W axis (reference quirk)
                const float ry = ku + dx;     // pairs with H axis
                int x0 = (int)rx;             // trunc == astype(int32)
                int x1 = x0 + 1;
                int y0 = (int)ry;
                int y1 = y0 + 1;
                int x0c = min(max(x0, 0), WW - 1);
                int x1c = min(max(x1, 0), WW - 1);
                int y0c = min(max(y0, 0), HH - 1);
                int y1c = min(max(y1, 0), HH - 1);
                const float fx0 = (float)x0c, fx1 = (float)x1c;
                const float fy0 = (float)y0c, fy1 = (float)y1c;
                const float w0v = (fy1 - ry)  * (fx1 - rx);
                const float w1v = (fy1 - byv) * (rx - fx0);
                const float w2v = (ry - fy0)  * (fx1 - rx);
                const float w3v = (ry - fy0)  * (rx - fx0);
                const float s00 = Sb[y0c * WW + x0c];
                const float s01 = Sb[y0c * WW + x1c];
                const float s10 = Sb[y1c * WW + x0c];
                const float s11 = Sb[y1c * WW + x1c];
                out[(size_t)(((b * 2 + g) * OH + oy) * OW + ox) * NTAP + tn]
                    = w0v * s00 + w1v * s01 + w2v * s10 + w3v * s11;
            }
        }
    }
}

extern "C" void kernel_launch(void* const* d_in, const int* in_sizes, int n_in,
                              void* d_out, int out_size, void* d_ws, size_t ws_size,
                              hipStream_t stream) {
    const float* vol   = (const float*)d_in[0];
    const float* w_off = (const float*)d_in[1];
    const float* b_off = (const float*)d_in[2];
    float* out = (float*)d_out;

    float* S   = (float*)d_ws;                                   // 576 KiB
    float* w_t = (float*)((char*)d_ws + 2 * HH * WW * 4);        // 160 KB

    const int nS = 2 * HH * WW;
    sumc_kernel<<<(nS + 255) / 256, 256, 0, stream>>>(vol, S, nS);

    const int nW = NTAP * 25 * 16;
    wtrans_kernel<<<(nW + 255) / 256, 256, 0, stream>>>(w_off, (float4*)w_t);

    dim3 grid((OW + TILE - 1) / TILE, 46, 2 * 2 * 5);   // 6 x 46 x 20
    dconv_kernel<<<grid, 320, 0, stream>>>(vol, w_t, b_off, S, out);
}

// Round 5
// 222.486 us; speedup vs baseline: 80.5272x; 1.0053x over previous
//
#include <hip/hip_runtime.h>

#define HH 192
#define WW 384
#define CC 16
#define OH 184
#define OW 376
#define NTAP 25
#define TILE 64

// Kernel A: S[b][y][x] = sum_c volume[...]; first NW threads also transpose weights:
// w_t[tn][kk][c][j] = w_off[kk][c][4*tn+j]
__global__ void prep_kernel(const float* __restrict__ vol, float* __restrict__ S,
                            const float* __restrict__ w_off, float4* __restrict__ w_t,
                            int nS, int nW) {
    int idx = blockIdx.x * 256 + threadIdx.x;
    if (idx < nS) {
        const float4* p = reinterpret_cast<const float4*>(vol + (size_t)idx * CC);
        float4 a = p[0], b = p[1], c = p[2], d = p[3];
        S[idx] = ((a.x + a.y) + (a.z + a.w)) + ((b.x + b.y) + (b.z + b.w))
               + ((c.x + c.y) + (c.z + c.w)) + ((d.x + d.y) + (d.z + d.w));
    }
    if (idx < nW) {
        int kk = (idx >> 4) % 25;
        int tn = idx / (25 * 16);
        w_t[idx] = *reinterpret_cast<const float4*>(w_off + ((idx & 15) + kk * 16) * 100 + 4 * tn);
    }
}

// 16 FMAs: acc.{x,y,z,w} += dot(v, channel-quad weights w0..w3)
#define DOT4Q(acc, v, w0, w1, w2, w3) do {                                   \
    acc.x = fmaf(v.x, w0.x, acc.x); acc.x = fmaf(v.y, w1.x, acc.x);          \
    acc.x = fmaf(v.z, w2.x, acc.x); acc.x = fmaf(v.w, w3.x, acc.x);          \
    acc.y = fmaf(v.x, w0.y, acc.y); acc.y = fmaf(v.y, w1.y, acc.y);          \
    acc.y = fmaf(v.z, w2.y, acc.y); acc.y = fmaf(v.w, w3.y, acc.y);          \
    acc.z = fmaf(v.x, w0.z, acc.z); acc.z = fmaf(v.y, w1.z, acc.z);          \
    acc.z = fmaf(v.z, w2.z, acc.z); acc.z = fmaf(v.w, w3.z, acc.z);          \
    acc.w = fmaf(v.x, w0.w, acc.w); acc.w = fmaf(v.y, w1.w, acc.w);          \
    acc.w = fmaf(v.z, w2.w, acc.w); acc.w = fmaf(v.w, w3.w, acc.w);          \
} while (0)

// Fused dilated 5x5 offset conv + bilinear sampling, 4 same-parity output rows/block.
// Block: 320 thr = 5 waves; wave = tap tn (wave-uniform -> weights via scalar loads).
// Rows oy_j = p + 8*gy + 2j (j=0..3) share dilated input rows -> 8-row LDS tile;
// each 16-float weight chunk (1x s_load_dwordx16) feeds 256 FMAs (4 row-accs).
__global__ __launch_bounds__(320) void dconv_kernel(
    const float* __restrict__ vol, const float* __restrict__ w_t,
    const float* __restrict__ b_off, const float* __restrict__ S,
    float* __restrict__ out)
{
    __shared__ float4 lds[4][8][73];   // [ch-quad][row][col]  37,376 B

    const int tid  = threadIdx.x;
    const int lane = tid & 63;
    const int wid  = tid >> 6;          // 0..4
    const int z    = blockIdx.z;        // ((b*2+p)*5 + kg)
    const int kg   = z % 5;
    const int rem  = z / 5;
    const int p    = rem & 1;
    const int b    = rem >> 1;
    const int gy   = blockIdx.y;        // 0..22
    const int ox0  = blockIdx.x * TILE;
    const int tn   = __builtin_amdgcn_readfirstlane(kg * 5 + wid);

    // stage 8 rows: global row = p + 8*gy + 2*t, t=0..7; cols ox0..ox0+71 (clamped)
    {
        const float* __restrict__ vb = vol + (size_t)((b * HH + p + 8 * gy) * WW) * CC;
        if (tid < 288) {                       // 72 cols x 4 quads per row
            const int q    = tid & 3;
            const int colr = tid >> 2;
            int colg = ox0 + colr; if (colg > WW - 1) colg = WW - 1;
            const float* src = vb + (size_t)colg * CC + 4 * q;
            #pragma unroll
            for (int t = 0; t < 8; ++t)
                lds[q][t][colr] = *reinterpret_cast<const float4*>(src + (size_t)(2 * t) * WW * CC);
        }
    }
    __syncthreads();

    const float4* __restrict__ wt = reinterpret_cast<const float4*>(w_t) + tn * (25 * 16); // uniform
    const float4 bo = *reinterpret_cast<const float4*>(b_off + 4 * tn);
    float4 acc0 = bo, acc1 = bo, acc2 = bo, acc3 = bo;

    #pragma unroll 1
    for (int r = 0; r < 5; ++r) {
        #pragma unroll
        for (int kx = 0; kx < 5; ++kx) {
            const float4* __restrict__ W = wt + (r * 5 + kx) * 16;
            const int cl = lane + 2 * kx;
            #pragma unroll
            for (int cq = 0; cq < 4; ++cq) {
                const float4 w0 = W[4 * cq + 0], w1 = W[4 * cq + 1];
                const float4 w2 = W[4 * cq + 2], w3 = W[4 * cq + 3];
                const float4 v0 = lds[cq][r + 0][cl];
                const float4 v1 = lds[cq][r + 1][cl];
                const float4 v2 = lds[cq][r + 2][cl];
                const float4 v3 = lds[cq][r + 3][cl];
                DOT4Q(acc0, v0, w0, w1, w2, w3);
                DOT4Q(acc1, v1, w0, w1, w2, w3);
                DOT4Q(acc2, v2, w0, w1, w2, w3);
                DOT4Q(acc3, v3, w0, w1, w2, w3);
            }
        }
    }

    // sampling epilogue: lane's pixel, tap tn, 4 rows x 2 groups
    const int ox = ox0 + lane;
    if (ox < OW) {
        const int kyt = tn / 5, kxt = tn % 5;
        const float kv = (float)(2 * kyt - 4);
        const float ku = (float)(2 * kxt - 4);
        const float* __restrict__ Sb = S + b * HH * WW;
        #pragma unroll
        for (int j = 0; j < 4; ++j) {
            const int oy = p + 8 * gy + 2 * j;
            const float4 acc = j == 0 ? acc0 : j == 1 ? acc1 : j == 2 ? acc2 : acc3;
            const float byv = (float)(4 + oy);
            #pragma unroll
            for (int g = 0; g < 2; ++g) {
                const float dy = g == 0 ? acc.x : acc.y;
                const float dx = g == 0 ? acc.z : acc.w;
                const float rx = kv + dy;     // pairs with W axis (reference quirk)
                const float ry = ku + dx;     // pairs with H axis
                int x0 = (int)rx;             // trunc == astype(int32)
                int x1 = x0 + 1;
                int y0 = (int)ry;
                int y1 = y0 + 1;
                int x0c = min(max(x0, 0), WW - 1);
                int x1c = min(max(x1, 0), WW - 1);
                int y0c = min(max(y0, 0), HH - 1);
                int y1c = min(max(y1, 0), HH - 1);
                const float fx0 = (float)x0c, fx1 = (float)x1c;
                const float fy0 = (float)y0c, fy1 = (float)y1c;
                const float w0v = (fy1 - ry)  * (fx1 - rx);
                const float w1v = (fy1 - byv) * (rx - fx0);
                const float w2v = (ry - fy0)  * (fx1 - rx);
                const float w3v = (ry - fy0)  * (rx - fx0);
                const float s00 = Sb[y0c * WW + x0c];
                const float s01 = Sb[y0c * WW + x1c];
                const float s10 = Sb[y1c * WW + x0c];
                const float s11 = Sb[y1c * WW + x1c];
                out[(size_t)(((b * 2 + g) * OH + oy) * OW + ox) * NTAP + tn]
                    = w0v * s00 + w1v * s01 + w2v * s10 + w3v * s11;
            }
        }
    }
}

extern "C" void kernel_launch(void* const* d_in, const int* in_sizes, int n_in,
                              void* d_out, int out_size, void* d_ws, size_t ws_size,
                              hipStream_t stream) {
    const float* vol   = (const float*)d_in[0];
    const float* w_off = (const float*)d_in[1];
    const float* b_off = (const float*)d_in[2];
    float* out = (float*)d_out;

    float* S   = (float*)d_ws;                                   // 576 KiB
    float* w_t = (float*)((char*)d_ws + 2 * HH * WW * 4);        // 160 KB

    const int nS = 2 * HH * WW;
    const int nW = NTAP * 25 * 16;
    prep_kernel<<<(nS + 255) / 256, 256, 0, stream>>>(vol, S, w_off, (float4*)w_t, nS, nW);

    dim3 grid((OW + TILE - 1) / TILE, 23, 2 * 2 * 5);   // 6 x 23 x 20
    dconv_kernel<<<grid, 320, 0, stream>>>(vol, w_t, b_off, S, out);
}